// Round 7
// baseline (1875.920 us; speedup 1.0000x reference)
//
#include <hip/hip_runtime.h>
#include <math.h>

// =====================================================================
// 3-layer GAT (PyG GATConv) on MI355X.
// R15: dispatch-count collapse 14 -> 4 (memset + 3 kernels).
//  - fused_front: CSR build + weight prep + layer-1 x-space aggregation,
//    6 device-wide barriers (hand-rolled, device-scope atomics+fences).
//  - gemm_async<16,4>: unchanged R13 kernel (64 KB LDS isolated).
//  - fused_back: agg_m4(L2) -> gemm3(CT=2, 8 KB LDS) -> agg_h1, 2 barriers.
//  Co-residency guaranteed: LDS<=8KB & VGPR<=64 (launch_bounds(512,8))
//  give 4 blocks/CU capacity; grids (512, 1000) are under 1024 cap.
// =====================================================================

#define NEG_SLOPE 0.2f
#define NT 512
#define NB1 512            // fused_front grid
#define SEG 98             // ceil(50000/512)
#define NB3 1000           // fused_back grid
#define NTILES 391         // ceil(50000/128) gemm tiles

typedef unsigned short u16;
typedef short bf16x8 __attribute__((ext_vector_type(8)));
typedef float floatx4 __attribute__((ext_vector_type(4)));

__device__ __forceinline__ float b2f(u16 u) {
    return __uint_as_float(((unsigned int)u) << 16);
}
__device__ __forceinline__ u16 f2b(float f) {
    unsigned int u = __float_as_uint(f);
    unsigned int r = (u + 0x7fffu + ((u >> 16) & 1u)) >> 16;   // RNE
    return (u16)r;
}
__device__ __forceinline__ void load16(const u16* g, u16* l) {
    __builtin_amdgcn_global_load_lds(
        (const __attribute__((address_space(1))) void*)g,
        (__attribute__((address_space(3))) void*)l, 16, 0, 0);
}

// ---- device-wide barrier (sense-reversal; bar[0]=count, bar[1]=gen) ----
// __threadfence = device-scope fence: writes back / invalidates per-XCD L2
// (same visibility a kernel boundary provides). Atomics are device-scope.
__device__ __forceinline__ void gridbar(int* bar, int nb) {
    __threadfence();
    __syncthreads();
    if (threadIdx.x == 0) {
        int g = atomicAdd(&bar[1], 0);
        if (atomicAdd(&bar[0], 1) == nb - 1) {
            atomicExch(&bar[0], 0);
            atomicAdd(&bar[1], 1);
        } else {
            while (atomicAdd(&bar[1], 0) == g) __builtin_amdgcn_s_sleep(8);
        }
    }
    __syncthreads();
    __threadfence();
}

// -------- Pack W into MFMA-fragment-major hi/lo bf16 (device) -------------

__device__ __forceinline__ void pack_dev(const float* __restrict__ W,
                                         u16* __restrict__ Bhi,
                                         u16* __restrict__ Blo, int N, int idx) {
    int CT = N / 16;
    int lane = idx & 63;
    int ctkb = idx >> 6;
    int ct = ctkb % CT;
    int kb = ctkb / CT;
    int col = ct * 16 + (lane & 15);
    int k0 = kb * 32 + (lane >> 4) * 8;
#pragma unroll
    for (int j = 0; j < 8; ++j) {
        float w = W[(size_t)(k0 + j) * N + col];
        u16 hi = f2b(w);
        Bhi[(size_t)idx * 8 + j] = hi;
        Blo[(size_t)idx * 8 + j] = f2b(w - b2f(hi));
    }
}

// ---------------- Layer-1 x-space aggregation (device, one node) ----------

__device__ __forceinline__ void agg_l1_node(int node, int lane,
                                            const float* __restrict__ x,
                                            const float* __restrict__ vsd,
                                            const int* __restrict__ offs,
                                            const int* __restrict__ csr,
                                            const float* __restrict__ W1,
                                            const float* __restrict__ bias,
                                            u16* __restrict__ outHi,
                                            u16* __restrict__ outLo) {
    const int hB = lane & 3;
    const int eL = lane >> 2;
    const int hA = lane >> 4;
    int beg = offs[node], end = offs[node + 1];

    float vs0 = vsd[hB * 3 + 0], vs1 = vsd[hB * 3 + 1], vs2 = vsd[hB * 3 + 2];
    float vd0 = vsd[12 + hB * 3 + 0], vd1 = vsd[12 + hB * 3 + 1], vd2 = vsd[12 + hB * 3 + 2];
    float xd0 = x[node * 3 + 0], xd1 = x[node * 3 + 1], xd2 = x[node * 3 + 2];
    float sd = fmaf(xd0, vd0, fmaf(xd1, vd1, xd2 * vd2));

    float m = -INFINITY, l = 0.f;
    float ax = 0.f, ay = 0.f, az = 0.f;

    for (int base = beg; base < end; base += 16) {
        int j = base + eL;
        bool valid = (j < end);
        int sj = valid ? csr[j] : 0;
        float x0 = x[sj * 3 + 0];
        float x1 = x[sj * 3 + 1];
        float x2 = x[sj * 3 + 2];
        float logit = -INFINITY;
        if (valid) {
            float xv = fmaf(x0, vs0, fmaf(x1, vs1, x2 * vs2)) + sd;
            logit = (xv > 0.f) ? xv : NEG_SLOPE * xv;
        }
        float cm = logit;
        cm = fmaxf(cm, __shfl_xor(cm, 4));
        cm = fmaxf(cm, __shfl_xor(cm, 8));
        cm = fmaxf(cm, __shfl_xor(cm, 16));
        cm = fmaxf(cm, __shfl_xor(cm, 32));
        float nm = fmaxf(m, cm);
        float scale = __expf(m - nm);
        float ex = valid ? __expf(logit - nm) : 0.f;
        float es = ex;
        es += __shfl_xor(es, 4);
        es += __shfl_xor(es, 8);
        es += __shfl_xor(es, 16);
        es += __shfl_xor(es, 32);
        l = l * scale + es;
        m = nm;
        float sA = __shfl(scale, hA);
        ax *= sA; ay *= sA; az *= sA;

        int cnt = min(16, end - base);
        for (int t = 0; t < cnt; ++t) {
            float a  = __shfl(ex, t * 4 + hA);
            float bx = __shfl(x0, t * 4);
            float by = __shfl(x1, t * 4);
            float bz = __shfl(x2, t * 4);
            ax = fmaf(a, bx, ax);
            ay = fmaf(a, by, ay);
            az = fmaf(a, bz, az);
        }
    }

    float lf = __shfl(l, hA);
    float inv = 1.f / lf;
    ax *= inv; ay *= inv; az *= inv;

    int c = lane * 4;
    const float4 w0 = *(const float4*)&W1[0 * 256 + c];
    const float4 w1 = *(const float4*)&W1[1 * 256 + c];
    const float4 w2 = *(const float4*)&W1[2 * 256 + c];
    const float4 bv = *(const float4*)&bias[c];
    float4 o;
    o.x = fmaxf(fmaf(ax, w0.x, fmaf(ay, w1.x, fmaf(az, w2.x, bv.x))), 0.f);
    o.y = fmaxf(fmaf(ax, w0.y, fmaf(ay, w1.y, fmaf(az, w2.y, bv.y))), 0.f);
    o.z = fmaxf(fmaf(ax, w0.z, fmaf(ay, w1.z, fmaf(az, w2.z, bv.z))), 0.f);
    o.w = fmaxf(fmaf(ax, w0.w, fmaf(ay, w1.w, fmaf(az, w2.w, bv.w))), 0.f);
    ushort4 h4, l4;
    h4.x = f2b(o.x); l4.x = f2b(o.x - b2f(h4.x));
    h4.y = f2b(o.y); l4.y = f2b(o.y - b2f(h4.y));
    h4.z = f2b(o.z); l4.z = f2b(o.z - b2f(h4.z));
    h4.w = f2b(o.w); l4.w = f2b(o.w - b2f(h4.w));
    *(ushort4*)&outHi[(size_t)node * 256 + c] = h4;
    *(ushort4*)&outLo[(size_t)node * 256 + c] = l4;
}

// ---------------- Merged 4-head aggregation (device, one node) ------------

__device__ __forceinline__ void agg_m4_node(int node, int lane,
                                            const u16* __restrict__ Hb,
                                            const float* __restrict__ ssrc,
                                            const float* __restrict__ sdst,
                                            const int* __restrict__ offs,
                                            const int* __restrict__ csr,
                                            const float* __restrict__ bias,
                                            u16* __restrict__ outHi,
                                            u16* __restrict__ outLo) {
    const int hB = lane & 3;
    const int eL = lane >> 2;
    const int hA = lane >> 4;
    int beg = offs[node], end = offs[node + 1];
    float sd = sdst[node * 4 + hB];
    float m = -INFINITY, l = 0.f;
    float4 acc = make_float4(0.f, 0.f, 0.f, 0.f);

    for (int base = beg; base < end; base += 16) {
        int j = base + eL;
        bool valid = (j < end);
        int sj = valid ? csr[j] : 0;
        float logit = -INFINITY;
        if (valid) {
            float xv = ssrc[sj * 4 + hB] + sd;
            logit = (xv > 0.f) ? xv : NEG_SLOPE * xv;
        }
        float cm = logit;
        cm = fmaxf(cm, __shfl_xor(cm, 4));
        cm = fmaxf(cm, __shfl_xor(cm, 8));
        cm = fmaxf(cm, __shfl_xor(cm, 16));
        cm = fmaxf(cm, __shfl_xor(cm, 32));
        float nm = fmaxf(m, cm);
        float scale = __expf(m - nm);
        float ex = valid ? __expf(logit - nm) : 0.f;
        float es = ex;
        es += __shfl_xor(es, 4);
        es += __shfl_xor(es, 8);
        es += __shfl_xor(es, 16);
        es += __shfl_xor(es, 32);
        l = l * scale + es;
        m = nm;
        float sA = __shfl(scale, hA);
        acc.x *= sA; acc.y *= sA; acc.z *= sA; acc.w *= sA;

        int cnt = min(16, end - base);
        for (int t = 0; t < cnt; t += 4) {
#pragma unroll
            for (int u = 0; u < 4; ++u) {
                int tt = t + u;
                float a = __shfl(ex, tt * 4 + hA);
                int s = __shfl(sj, tt * 4);
                ushort4 hv = *(const ushort4*)&Hb[(size_t)s * 256 + lane * 4];
                acc.x = fmaf(a, b2f(hv.x), acc.x);
                acc.y = fmaf(a, b2f(hv.y), acc.y);
                acc.z = fmaf(a, b2f(hv.z), acc.z);
                acc.w = fmaf(a, b2f(hv.w), acc.w);
            }
        }
    }
    float lf = __shfl(l, hA);
    float inv = 1.f / lf;
    const float4 bv = *(const float4*)&bias[lane * 4];
    float4 o;
    o.x = fmaxf(fmaf(acc.x, inv, bv.x), 0.f);
    o.y = fmaxf(fmaf(acc.y, inv, bv.y), 0.f);
    o.z = fmaxf(fmaf(acc.z, inv, bv.z), 0.f);
    o.w = fmaxf(fmaf(acc.w, inv, bv.w), 0.f);
    ushort4 h4, l4;
    h4.x = f2b(o.x); l4.x = f2b(o.x - b2f(h4.x));
    h4.y = f2b(o.y); l4.y = f2b(o.y - b2f(h4.y));
    h4.z = f2b(o.z); l4.z = f2b(o.z - b2f(h4.z));
    h4.w = f2b(o.w); l4.w = f2b(o.w - b2f(h4.w));
    *(ushort4*)&outHi[(size_t)node * 256 + lane * 4] = h4;
    *(ushort4*)&outLo[(size_t)node * 256 + lane * 4] = l4;
}

// ---------------- Single-head aggregation (device, one node) --------------

__device__ __forceinline__ void agg_h1_node(int node, int lane,
                                            const u16* __restrict__ Hb,
                                            const float* __restrict__ ssrc,
                                            const float* __restrict__ sdst,
                                            const int* __restrict__ offs,
                                            const int* __restrict__ csr,
                                            const float* __restrict__ bias,
                                            float* __restrict__ out) {
    int beg = offs[node], end = offs[node + 1];
    float sd = sdst[node];
    float m = -INFINITY, l = 0.f, acc = 0.f;

    for (int base = beg; base < end; base += 64) {
        int j = base + lane;
        bool valid = (j < end);
        int sj = valid ? csr[j] : 0;
        float logit = -INFINITY;
        if (valid) {
            float xv = ssrc[sj] + sd;
            logit = (xv > 0.f) ? xv : NEG_SLOPE * xv;
        }
        float cm = logit;
#pragma unroll
        for (int o = 32; o > 0; o >>= 1) cm = fmaxf(cm, __shfl_xor(cm, o));
        float nm = fmaxf(m, cm);
        float scale = __expf(m - nm);
        float ex = valid ? __expf(logit - nm) : 0.f;
        float es = ex;
#pragma unroll
        for (int o = 32; o > 0; o >>= 1) es += __shfl_xor(es, o);
        l = l * scale + es;
        m = nm;
        acc *= scale;
        int cnt = min(64, end - base);
        for (int t = 0; t < cnt; t += 4) {
#pragma unroll
            for (int u = 0; u < 4; ++u) {
                float a = __shfl(ex, t + u);
                int s = __shfl(sj, t + u);
                if (lane < 32) acc = fmaf(a, b2f(Hb[(size_t)s * 32 + lane]), acc);
            }
        }
    }
    if (lane < 32) out[(size_t)node * 32 + lane] = acc / l + bias[lane];
}

// ------- Async 2-phase split-precision MFMA GEMM body (BM=128, 8 waves) ---

template <int CT, int HEADS>
__device__ __forceinline__ void gemm_phase(u16* ldsb,
                                           const u16* __restrict__ Ahi,
                                           const u16* __restrict__ Alo,
                                           const u16* __restrict__ Bhi,
                                           const u16* __restrict__ Blo,
                                           const float* __restrict__ asrc,
                                           const float* __restrict__ adst,
                                           u16* __restrict__ Hb,
                                           float* __restrict__ ssrc,
                                           float* __restrict__ sdst, int n) {
    constexpr int THREADS = 512;
    constexpr int BFRAG = CT * 64;          // B 16B-chunks per kb per array
    constexpr int BSZ = BFRAG * 8;          // u16 per B array per kb slice

    int t = threadIdx.x;
    int w = t >> 6, l = t & 63;
    int m0 = blockIdx.x * 128 + w * 16;
    int lm = l & 15, q = l >> 4;

    int arow = min(m0 + lm, n - 1);
    const u16* aH = Ahi + (size_t)arow * 256 + q * 8;
    const u16* aL = Alo + (size_t)arow * 256 + q * 8;

    floatx4 acc[CT] = {};

    auto stageB = [&](int buf, int kb) {
        u16* L = ldsb + (size_t)buf * (2 * BSZ);
        constexpr int BROUNDS = (BFRAG + THREADS - 1) / THREADS;
#pragma unroll
        for (int r = 0; r < BROUNDS; ++r) {
            int u = r * THREADS + t;
            if ((BFRAG % THREADS == 0) || u < BFRAG) {
                size_t off = ((size_t)kb * BFRAG + (size_t)u) * 8;
                u16* Lb = L + (size_t)(r * THREADS + w * 64) * 8;
                load16(Bhi + off, Lb);
                load16(Blo + off, Lb + BSZ);
            }
        }
    };

    stageB(0, 0);
    bf16x8 ahi = *(const bf16x8*)aH;
    bf16x8 alo = *(const bf16x8*)aL;
    __syncthreads();

    for (int kb = 0; kb < 8; ++kb) {
        int cur = kb & 1;
        bf16x8 nhi = ahi, nlo = alo;
        if (kb < 7) {
            stageB(cur ^ 1, kb + 1);
            nhi = *(const bf16x8*)(aH + (kb + 1) * 32);
            nlo = *(const bf16x8*)(aL + (kb + 1) * 32);
        }
        const u16* L = ldsb + (size_t)cur * (2 * BSZ);
#pragma unroll
        for (int ct = 0; ct < CT; ++ct) {
            bf16x8 bhi = *(const bf16x8*)&L[(ct * 64 + l) * 8];
            bf16x8 blo = *(const bf16x8*)&L[BSZ + (ct * 64 + l) * 8];
            acc[ct] = __builtin_amdgcn_mfma_f32_16x16x32_bf16(ahi, bhi, acc[ct], 0, 0, 0);
            acc[ct] = __builtin_amdgcn_mfma_f32_16x16x32_bf16(alo, bhi, acc[ct], 0, 0, 0);
            acc[ct] = __builtin_amdgcn_mfma_f32_16x16x32_bf16(ahi, blo, acc[ct], 0, 0, 0);
        }
        __syncthreads();
        ahi = nhi; alo = nlo;
    }

#pragma unroll
    for (int ct = 0; ct < CT; ++ct) {
#pragma unroll
        for (int r = 0; r < 4; ++r) {
            int row = m0 + q * 4 + r;
            if (row < n)
                Hb[(size_t)row * (CT * 16) + ct * 16 + lm] = f2b(acc[ct][r]);
        }
    }
    constexpr int CPH = CT / HEADS;
    float ps[4][HEADS] = {}, pd[4][HEADS] = {};
#pragma unroll
    for (int h = 0; h < HEADS; ++h) {
#pragma unroll
        for (int j = 0; j < CPH; ++j) {
            int ct = h * CPH + j;
            float a_s = asrc[ct * 16 + lm];
            float a_d = adst[ct * 16 + lm];
#pragma unroll
            for (int r = 0; r < 4; ++r) {
                ps[r][h] = fmaf(acc[ct][r], a_s, ps[r][h]);
                pd[r][h] = fmaf(acc[ct][r], a_d, pd[r][h]);
            }
        }
    }
#pragma unroll
    for (int r = 0; r < 4; ++r)
#pragma unroll
        for (int h = 0; h < HEADS; ++h)
#pragma unroll
            for (int o = 1; o < 16; o <<= 1) {
                ps[r][h] += __shfl_xor(ps[r][h], o);
                pd[r][h] += __shfl_xor(pd[r][h], o);
            }
#pragma unroll
    for (int h = 0; h < HEADS; ++h) {
        if (lm == h) {
#pragma unroll
            for (int r = 0; r < 4; ++r) {
                int row = m0 + q * 4 + r;
                if (row < n) {
                    ssrc[row * HEADS + h] = ps[r][h];
                    sdst[row * HEADS + h] = pd[r][h];
                }
            }
        }
    }
}

// ---------------- K2: layer-2 GEMM (unchanged R13 structure) --------------

template <int CT, int HEADS>
__global__ __launch_bounds__(512, 4) void gemm_async(const u16* __restrict__ Ahi,
                                                     const u16* __restrict__ Alo,
                                                     const u16* __restrict__ Bhi,
                                                     const u16* __restrict__ Blo,
                                                     const float* __restrict__ asrc,
                                                     const float* __restrict__ adst,
                                                     u16* __restrict__ Hb,
                                                     float* __restrict__ ssrc,
                                                     float* __restrict__ sdst, int n) {
    __shared__ __align__(16) u16 lds[2][2 * CT * 64 * 8];
    gemm_phase<CT, HEADS>(&lds[0][0], Ahi, Alo, Bhi, Blo, asrc, adst, Hb, ssrc, sdst, n);
}

// ---------------- K1: CSR build + prep + layer-1 aggregation --------------

__global__ __launch_bounds__(NT, 8) void fused_front(
    const float* __restrict__ x, const int* __restrict__ ei,
    const float* __restrict__ W1, const float* __restrict__ as1,
    const float* __restrict__ ad1, const float* __restrict__ b1,
    const float* __restrict__ W2, const float* __restrict__ W3,
    u16* __restrict__ B2h, u16* __restrict__ B2l,
    u16* __restrict__ B3h, u16* __restrict__ B3l,
    float* __restrict__ vsd,
    int* __restrict__ deg, int* __restrict__ offs, int* __restrict__ cursor,
    int* __restrict__ partial, int* __restrict__ csr, int* __restrict__ bar,
    u16* __restrict__ Fhi, u16* __restrict__ Flo, int n, int E) {
    __shared__ int sci[NT];
    const int tid = threadIdx.x;
    const int b = blockIdx.x;
    const int tg = b * NT + tid;
    const int NTH = NB1 * NT;
    const int Etot = E + n;

    // ---- P0: zero deg + pack W2/W3 + l1_prep ----
    for (int i = tg; i < n; i += NTH) deg[i] = 0;
    if (tg < 8192) {
        pack_dev(W2, B2h, B2l, 256, tg);
    } else if (tg < 9216) {
        pack_dev(W3, B3h, B3l, 32, tg - 8192);
    } else if (tg < 9472) {
        int j = tg - 9216;                 // 0..255, wave-aligned (9216%64==0)
        int lane = j & 63;
        float a_s = as1[j], a_d = ad1[j];
#pragma unroll
        for (int k = 0; k < 3; ++k) {
            float w = W1[k * 256 + j];
            float ps = w * a_s, pd = w * a_d;
#pragma unroll
            for (int o = 32; o > 0; o >>= 1) {
                ps += __shfl_xor(ps, o);
                pd += __shfl_xor(pd, o);
            }
            if (lane == 0) {
                vsd[(j >> 6) * 3 + k] = ps;
                vsd[12 + (j >> 6) * 3 + k] = pd;
            }
        }
    }
    gridbar(bar, NB1);

    // ---- P1: edge count ----
    for (int e = tg; e < Etot; e += NTH) {
        int dst = (e < E) ? ei[E + e] : (e - E);
        atomicAdd(&deg[dst], 1);
    }
    gridbar(bar, NB1);

    // ---- P2: per-block segment sums (SEG=98 per block) ----
    {
        int i0 = b * SEG + tid;
        int v = (tid < SEG && i0 < n) ? deg[i0] : 0;
        sci[tid] = v;
        __syncthreads();
        for (int off = 256; off > 0; off >>= 1) {
            if (tid < off) sci[tid] += sci[tid + off];
            __syncthreads();
        }
        if (tid == 0) partial[b] = sci[0];
    }
    gridbar(bar, NB1);

    // ---- P3: block 0 scans the 512 partials ----
    if (b == 0) {
        int v = partial[tid];
        sci[tid] = v;
        __syncthreads();
        for (int off = 1; off < NT; off <<= 1) {
            int t2 = (tid >= off) ? sci[tid - off] : 0;
            __syncthreads();
            sci[tid] += t2;
            __syncthreads();
        }
        partial[tid] = sci[tid] - v;       // exclusive
        if (tid == NT - 1) offs[n] = sci[tid];
    }
    gridbar(bar, NB1);

    // ---- P4: per-block exclusive scan + offsets ----
    {
        int i0 = b * SEG + tid;
        int v = (tid < SEG && i0 < n) ? deg[i0] : 0;
        sci[tid] = v;
        __syncthreads();
        for (int off = 1; off < NT; off <<= 1) {
            int t2 = (tid >= off) ? sci[tid - off] : 0;
            __syncthreads();
            sci[tid] += t2;
            __syncthreads();
        }
        int excl = sci[tid] - v + partial[b];
        if (tid < SEG && i0 < n) { offs[i0] = excl; cursor[i0] = excl; }
    }
    gridbar(bar, NB1);

    // ---- P5: edge fill ----
    for (int e = tg; e < Etot; e += NTH) {
        int src, dst;
        if (e < E) { src = ei[e]; dst = ei[E + e]; }
        else       { src = e - E; dst = e - E; }
        int pos = atomicAdd(&cursor[dst], 1);
        csr[pos] = src;
    }
    gridbar(bar, NB1);

    // ---- P6: layer-1 x-space aggregation ----
    {
        int wid = b * 8 + (tid >> 6);
        int lane = tid & 63;
        for (int node = wid; node < n; node += NB1 * 8)
            agg_l1_node(node, lane, x, vsd, offs, csr, W1, b1, Fhi, Flo);
    }
}

// ---------------- K3: agg_m4(L2) -> gemm3 -> agg_h1 -----------------------

__global__ __launch_bounds__(NT, 8) void fused_back(
    const u16* __restrict__ B3h, const u16* __restrict__ B3l,
    const float* __restrict__ as3, const float* __restrict__ ad3,
    const float* __restrict__ b2, const float* __restrict__ b3,
    u16* __restrict__ Fhi, u16* __restrict__ Flo,
    const u16* __restrict__ Hb, u16* __restrict__ Hb3,
    float* __restrict__ ssrc, float* __restrict__ sdst,
    const int* __restrict__ offs, const int* __restrict__ csr,
    int* __restrict__ bar, float* __restrict__ out, int n) {
    __shared__ __align__(16) u16 lds3[4096];   // 8 KB: CT=2 double-buffer
    const int tid = threadIdx.x;
    const int b = blockIdx.x;
    const int wid = b * 8 + (tid >> 6);
    const int lane = tid & 63;

    // ---- P8: layer-2 aggregation (reads Hb/ssrc/sdst; writes Fhi/Flo) ----
    for (int node = wid; node < n; node += NB3 * 8)
        agg_m4_node(node, lane, Hb, ssrc, sdst, offs, csr, b2, Fhi, Flo);
    gridbar(bar, NB3);

    // ---- P9: layer-3 GEMM (reads Fhi/Flo; writes Hb3, ssrc/sdst str.1) ---
    if (b < NTILES)
        gemm_phase<2, 1>(&lds3[0], Fhi, Flo, B3h, B3l, as3, ad3, Hb3, ssrc, sdst, n);
    gridbar(bar, NB3);

    // ---- P10: layer-3 aggregation -> out ----
    for (int node = wid; node < n; node += NB3 * 8)
        agg_h1_node(node, lane, Hb3, ssrc, sdst, offs, csr, b3, out);
}

// ---------------- Launch ----------------

extern "C" void kernel_launch(void* const* d_in, const int* in_sizes, int n_in,
                              void* d_out, int out_size, void* d_ws, size_t ws_size,
                              hipStream_t stream) {
    const float* x   = (const float*)d_in[0];
    const int*   ei  = (const int*)d_in[1];
    const float* W1  = (const float*)d_in[2];
    const float* as1 = (const float*)d_in[3];
    const float* ad1 = (const float*)d_in[4];
    const float* b1  = (const float*)d_in[5];
    const float* W2  = (const float*)d_in[6];
    const float* as2 = (const float*)d_in[7];
    const float* ad2 = (const float*)d_in[8];
    const float* b2  = (const float*)d_in[9];
    const float* W3  = (const float*)d_in[10];
    const float* as3 = (const float*)d_in[11];
    const float* ad3 = (const float*)d_in[12];
    const float* b3  = (const float*)d_in[13];
    float* out = (float*)d_out;

    const int n = in_sizes[0] / 3;     // 50000
    const int E = in_sizes[1] / 2;     // 400000
    const int Etot = E + n;            // with self-loops

    // workspace layout (~84 MB)
    char* ws = (char*)d_ws;
    u16* Fhi  = (u16*)ws;    ws += (size_t)n * 256 * sizeof(u16);     // 25.6 MB
    u16* Flo  = (u16*)ws;    ws += (size_t)n * 256 * sizeof(u16);     // 25.6 MB
    u16* Hb   = (u16*)ws;    ws += (size_t)n * 256 * sizeof(u16);     // 25.6 MB
    u16* Hb3  = (u16*)ws;    ws += (size_t)n * 32 * sizeof(u16);      // 3.2 MB
    u16* B2h  = (u16*)ws;    ws += (size_t)8 * 16 * 64 * 8 * sizeof(u16);
    u16* B2l  = (u16*)ws;    ws += (size_t)8 * 16 * 64 * 8 * sizeof(u16);
    u16* B3h  = (u16*)ws;    ws += (size_t)8 * 2 * 64 * 8 * sizeof(u16);
    u16* B3l  = (u16*)ws;    ws += (size_t)8 * 2 * 64 * 8 * sizeof(u16);
    float* ssrc = (float*)ws;  ws += (size_t)n * 4 * sizeof(float);
    float* sdst = (float*)ws;  ws += (size_t)n * 4 * sizeof(float);
    float* vsd  = (float*)ws;  ws += 32 * sizeof(float);
    int* deg    = (int*)ws;    ws += (size_t)n * sizeof(int);
    int* offs   = (int*)ws;    ws += (size_t)(n + 1) * sizeof(int) + 12;
    int* cursor = (int*)ws;    ws += (size_t)n * sizeof(int);
    int* partial = (int*)ws;   ws += (size_t)NT * sizeof(int);
    int* bar    = (int*)ws;    ws += 4 * sizeof(int);
    int* csr    = (int*)ws;    ws += (size_t)Etot * sizeof(int);   // keep csr LAST

    // ---- reset barrier state (count, gen) ----
    hipMemsetAsync(bar, 0, 4 * sizeof(int), stream);

    // ---- K1: CSR + prep + layer 1 ----
    fused_front<<<NB1, NT, 0, stream>>>(x, ei, W1, as1, ad1, b1, W2, W3,
                                        B2h, B2l, B3h, B3l, vsd,
                                        deg, offs, cursor, partial, csr, bar,
                                        Fhi, Flo, n, E);

    // ---- K2: layer-2 GEMM ----
    gemm_async<16, 4><<<NTILES, NT, 0, stream>>>(Fhi, Flo, B2h, B2l, as2, ad2,
                                                 Hb, ssrc, sdst, n);

    // ---- K3: layer-2 agg + layer-3 GEMM + layer-3 agg ----
    fused_back<<<NB3, NT, 0, stream>>>(B3h, B3l, as3, ad3, b2, b3,
                                       Fhi, Flo, Hb, Hb3, ssrc, sdst,
                                       offs, csr, bar, out, n);
}

// Round 8
// 1431.556 us; speedup vs baseline: 1.3104x; 1.3104x over previous
//
#include <hip/hip_runtime.h>
#include <math.h>

// =====================================================================
// 3-layer GAT (PyG GATConv) on MI355X.
// R16: R15 fusion with fixed grid barrier.
//  - gridbar: load-only polling (__hip_atomic_load, agent scope), cnt/gen
//    on separate 128B cache lines (R15 polled with RMWs on one line ->
//    ~150us/barrier of LLC serialization; that was the whole regression).
//  - fused_front barriers 6 -> 4: scan replaced by wave-atomic segment
//    allocation (shfl_up prefix + 1 atomicAdd/wave); consumers compute
//    end = offs[node] + deg[node] (segment order now arbitrary).
//  - Phase bodies byte-identical to R14/R15 proven kernels.
//  Dispatches: memset + fused_front + gemm_async<16,4> + fused_back.
// =====================================================================

#define NEG_SLOPE 0.2f
#define NT 512
#define NB1 512            // fused_front grid
#define NB3 1000           // fused_back grid
#define NTILES 391         // ceil(50000/128) gemm tiles

typedef unsigned short u16;
typedef short bf16x8 __attribute__((ext_vector_type(8)));
typedef float floatx4 __attribute__((ext_vector_type(4)));

__device__ __forceinline__ float b2f(u16 u) {
    return __uint_as_float(((unsigned int)u) << 16);
}
__device__ __forceinline__ u16 f2b(float f) {
    unsigned int u = __float_as_uint(f);
    unsigned int r = (u + 0x7fffu + ((u >> 16) & 1u)) >> 16;   // RNE
    return (u16)r;
}
__device__ __forceinline__ void load16(const u16* g, u16* l) {
    __builtin_amdgcn_global_load_lds(
        (const __attribute__((address_space(1))) void*)g,
        (__attribute__((address_space(3))) void*)l, 16, 0, 0);
}

// ---- device-wide barrier: cnt=bar[0], gen=bar[32] (separate lines) ----
// Arrival: one RMW per block. Wait: LOAD-only poll (no line ownership).
// __threadfence (device scope) before/after = L2 writeback/invalidate,
// same visibility a kernel boundary provides. Correctness proven in R15.
__device__ __forceinline__ void gridbar(int* bar, int nb) {
    __threadfence();
    __syncthreads();
    if (threadIdx.x == 0) {
        int* cnt = &bar[0];
        int* gen = &bar[32];
        int g = __hip_atomic_load(gen, __ATOMIC_RELAXED, __HIP_MEMORY_SCOPE_AGENT);
        if (atomicAdd(cnt, 1) == nb - 1) {
            __hip_atomic_store(cnt, 0, __ATOMIC_RELAXED, __HIP_MEMORY_SCOPE_AGENT);
            __hip_atomic_store(gen, g + 1, __ATOMIC_RELEASE, __HIP_MEMORY_SCOPE_AGENT);
        } else {
            while (__hip_atomic_load(gen, __ATOMIC_RELAXED, __HIP_MEMORY_SCOPE_AGENT) == g)
                __builtin_amdgcn_s_sleep(16);
        }
    }
    __syncthreads();
    __threadfence();
}

// -------- Pack W into MFMA-fragment-major hi/lo bf16 (device) -------------

__device__ __forceinline__ void pack_dev(const float* __restrict__ W,
                                         u16* __restrict__ Bhi,
                                         u16* __restrict__ Blo, int N, int idx) {
    int CT = N / 16;
    int lane = idx & 63;
    int ctkb = idx >> 6;
    int ct = ctkb % CT;
    int kb = ctkb / CT;
    int col = ct * 16 + (lane & 15);
    int k0 = kb * 32 + (lane >> 4) * 8;
#pragma unroll
    for (int j = 0; j < 8; ++j) {
        float w = W[(size_t)(k0 + j) * N + col];
        u16 hi = f2b(w);
        Bhi[(size_t)idx * 8 + j] = hi;
        Blo[(size_t)idx * 8 + j] = f2b(w - b2f(hi));
    }
}

// ---------------- Layer-1 x-space aggregation (device, one node) ----------

__device__ __forceinline__ void agg_l1_node(int node, int lane,
                                            const float* __restrict__ x,
                                            const float* __restrict__ vsd,
                                            const int* __restrict__ offs,
                                            const int* __restrict__ deg,
                                            const int* __restrict__ csr,
                                            const float* __restrict__ W1,
                                            const float* __restrict__ bias,
                                            u16* __restrict__ outHi,
                                            u16* __restrict__ outLo) {
    const int hB = lane & 3;
    const int eL = lane >> 2;
    const int hA = lane >> 4;
    int beg = offs[node], end = beg + deg[node];

    float vs0 = vsd[hB * 3 + 0], vs1 = vsd[hB * 3 + 1], vs2 = vsd[hB * 3 + 2];
    float vd0 = vsd[12 + hB * 3 + 0], vd1 = vsd[12 + hB * 3 + 1], vd2 = vsd[12 + hB * 3 + 2];
    float xd0 = x[node * 3 + 0], xd1 = x[node * 3 + 1], xd2 = x[node * 3 + 2];
    float sd = fmaf(xd0, vd0, fmaf(xd1, vd1, xd2 * vd2));

    float m = -INFINITY, l = 0.f;
    float ax = 0.f, ay = 0.f, az = 0.f;

    for (int base = beg; base < end; base += 16) {
        int j = base + eL;
        bool valid = (j < end);
        int sj = valid ? csr[j] : 0;
        float x0 = x[sj * 3 + 0];
        float x1 = x[sj * 3 + 1];
        float x2 = x[sj * 3 + 2];
        float logit = -INFINITY;
        if (valid) {
            float xv = fmaf(x0, vs0, fmaf(x1, vs1, x2 * vs2)) + sd;
            logit = (xv > 0.f) ? xv : NEG_SLOPE * xv;
        }
        float cm = logit;
        cm = fmaxf(cm, __shfl_xor(cm, 4));
        cm = fmaxf(cm, __shfl_xor(cm, 8));
        cm = fmaxf(cm, __shfl_xor(cm, 16));
        cm = fmaxf(cm, __shfl_xor(cm, 32));
        float nm = fmaxf(m, cm);
        float scale = __expf(m - nm);
        float ex = valid ? __expf(logit - nm) : 0.f;
        float es = ex;
        es += __shfl_xor(es, 4);
        es += __shfl_xor(es, 8);
        es += __shfl_xor(es, 16);
        es += __shfl_xor(es, 32);
        l = l * scale + es;
        m = nm;
        float sA = __shfl(scale, hA);
        ax *= sA; ay *= sA; az *= sA;

        int cnt = min(16, end - base);
        for (int t = 0; t < cnt; ++t) {
            float a  = __shfl(ex, t * 4 + hA);
            float bx = __shfl(x0, t * 4);
            float by = __shfl(x1, t * 4);
            float bz = __shfl(x2, t * 4);
            ax = fmaf(a, bx, ax);
            ay = fmaf(a, by, ay);
            az = fmaf(a, bz, az);
        }
    }

    float lf = __shfl(l, hA);
    float inv = 1.f / lf;
    ax *= inv; ay *= inv; az *= inv;

    int c = lane * 4;
    const float4 w0 = *(const float4*)&W1[0 * 256 + c];
    const float4 w1 = *(const float4*)&W1[1 * 256 + c];
    const float4 w2 = *(const float4*)&W1[2 * 256 + c];
    const float4 bv = *(const float4*)&bias[c];
    float4 o;
    o.x = fmaxf(fmaf(ax, w0.x, fmaf(ay, w1.x, fmaf(az, w2.x, bv.x))), 0.f);
    o.y = fmaxf(fmaf(ax, w0.y, fmaf(ay, w1.y, fmaf(az, w2.y, bv.y))), 0.f);
    o.z = fmaxf(fmaf(ax, w0.z, fmaf(ay, w1.z, fmaf(az, w2.z, bv.z))), 0.f);
    o.w = fmaxf(fmaf(ax, w0.w, fmaf(ay, w1.w, fmaf(az, w2.w, bv.w))), 0.f);
    ushort4 h4, l4;
    h4.x = f2b(o.x); l4.x = f2b(o.x - b2f(h4.x));
    h4.y = f2b(o.y); l4.y = f2b(o.y - b2f(h4.y));
    h4.z = f2b(o.z); l4.z = f2b(o.z - b2f(h4.z));
    h4.w = f2b(o.w); l4.w = f2b(o.w - b2f(h4.w));
    *(ushort4*)&outHi[(size_t)node * 256 + c] = h4;
    *(ushort4*)&outLo[(size_t)node * 256 + c] = l4;
}

// ---------------- Merged 4-head aggregation (device, one node) ------------

__device__ __forceinline__ void agg_m4_node(int node, int lane,
                                            const u16* __restrict__ Hb,
                                            const float* __restrict__ ssrc,
                                            const float* __restrict__ sdst,
                                            const int* __restrict__ offs,
                                            const int* __restrict__ deg,
                                            const int* __restrict__ csr,
                                            const float* __restrict__ bias,
                                            u16* __restrict__ outHi,
                                            u16* __restrict__ outLo) {
    const int hB = lane & 3;
    const int eL = lane >> 2;
    const int hA = lane >> 4;
    int beg = offs[node], end = beg + deg[node];
    float sd = sdst[node * 4 + hB];
    float m = -INFINITY, l = 0.f;
    float4 acc = make_float4(0.f, 0.f, 0.f, 0.f);

    for (int base = beg; base < end; base += 16) {
        int j = base + eL;
        bool valid = (j < end);
        int sj = valid ? csr[j] : 0;
        float logit = -INFINITY;
        if (valid) {
            float xv = ssrc[sj * 4 + hB] + sd;
            logit = (xv > 0.f) ? xv : NEG_SLOPE * xv;
        }
        float cm = logit;
        cm = fmaxf(cm, __shfl_xor(cm, 4));
        cm = fmaxf(cm, __shfl_xor(cm, 8));
        cm = fmaxf(cm, __shfl_xor(cm, 16));
        cm = fmaxf(cm, __shfl_xor(cm, 32));
        float nm = fmaxf(m, cm);
        float scale = __expf(m - nm);
        float ex = valid ? __expf(logit - nm) : 0.f;
        float es = ex;
        es += __shfl_xor(es, 4);
        es += __shfl_xor(es, 8);
        es += __shfl_xor(es, 16);
        es += __shfl_xor(es, 32);
        l = l * scale + es;
        m = nm;
        float sA = __shfl(scale, hA);
        acc.x *= sA; acc.y *= sA; acc.z *= sA; acc.w *= sA;

        int cnt = min(16, end - base);
        for (int t = 0; t < cnt; t += 4) {
#pragma unroll
            for (int u = 0; u < 4; ++u) {
                int tt = t + u;
                float a = __shfl(ex, tt * 4 + hA);
                int s = __shfl(sj, tt * 4);
                ushort4 hv = *(const ushort4*)&Hb[(size_t)s * 256 + lane * 4];
                acc.x = fmaf(a, b2f(hv.x), acc.x);
                acc.y = fmaf(a, b2f(hv.y), acc.y);
                acc.z = fmaf(a, b2f(hv.z), acc.z);
                acc.w = fmaf(a, b2f(hv.w), acc.w);
            }
        }
    }
    float lf = __shfl(l, hA);
    float inv = 1.f / lf;
    const float4 bv = *(const float4*)&bias[lane * 4];
    float4 o;
    o.x = fmaxf(fmaf(acc.x, inv, bv.x), 0.f);
    o.y = fmaxf(fmaf(acc.y, inv, bv.y), 0.f);
    o.z = fmaxf(fmaf(acc.z, inv, bv.z), 0.f);
    o.w = fmaxf(fmaf(acc.w, inv, bv.w), 0.f);
    ushort4 h4, l4;
    h4.x = f2b(o.x); l4.x = f2b(o.x - b2f(h4.x));
    h4.y = f2b(o.y); l4.y = f2b(o.y - b2f(h4.y));
    h4.z = f2b(o.z); l4.z = f2b(o.z - b2f(h4.z));
    h4.w = f2b(o.w); l4.w = f2b(o.w - b2f(h4.w));
    *(ushort4*)&outHi[(size_t)node * 256 + lane * 4] = h4;
    *(ushort4*)&outLo[(size_t)node * 256 + lane * 4] = l4;
}

// ---------------- Single-head aggregation (device, one node) --------------

__device__ __forceinline__ void agg_h1_node(int node, int lane,
                                            const u16* __restrict__ Hb,
                                            const float* __restrict__ ssrc,
                                            const float* __restrict__ sdst,
                                            const int* __restrict__ offs,
                                            const int* __restrict__ deg,
                                            const int* __restrict__ csr,
                                            const float* __restrict__ bias,
                                            float* __restrict__ out) {
    int beg = offs[node], end = beg + deg[node];
    float sd = sdst[node];
    float m = -INFINITY, l = 0.f, acc = 0.f;

    for (int base = beg; base < end; base += 64) {
        int j = base + lane;
        bool valid = (j < end);
        int sj = valid ? csr[j] : 0;
        float logit = -INFINITY;
        if (valid) {
            float xv = ssrc[sj] + sd;
            logit = (xv > 0.f) ? xv : NEG_SLOPE * xv;
        }
        float cm = logit;
#pragma unroll
        for (int o = 32; o > 0; o >>= 1) cm = fmaxf(cm, __shfl_xor(cm, o));
        float nm = fmaxf(m, cm);
        float scale = __expf(m - nm);
        float ex = valid ? __expf(logit - nm) : 0.f;
        float es = ex;
#pragma unroll
        for (int o = 32; o > 0; o >>= 1) es += __shfl_xor(es, o);
        l = l * scale + es;
        m = nm;
        acc *= scale;
        int cnt = min(64, end - base);
        for (int t = 0; t < cnt; t += 4) {
#pragma unroll
            for (int u = 0; u < 4; ++u) {
                float a = __shfl(ex, t + u);
                int s = __shfl(sj, t + u);
                if (lane < 32) acc = fmaf(a, b2f(Hb[(size_t)s * 32 + lane]), acc);
            }
        }
    }
    if (lane < 32) out[(size_t)node * 32 + lane] = acc / l + bias[lane];
}

// ------- Async 2-phase split-precision MFMA GEMM body (BM=128, 8 waves) ---

template <int CT, int HEADS>
__device__ __forceinline__ void gemm_phase(u16* ldsb,
                                           const u16* __restrict__ Ahi,
                                           const u16* __restrict__ Alo,
                                           const u16* __restrict__ Bhi,
                                           const u16* __restrict__ Blo,
                                           const float* __restrict__ asrc,
                                           const float* __restrict__ adst,
                                           u16* __restrict__ Hb,
                                           float* __restrict__ ssrc,
                                           float* __restrict__ sdst, int n) {
    constexpr int THREADS = 512;
    constexpr int BFRAG = CT * 64;          // B 16B-chunks per kb per array
    constexpr int BSZ = BFRAG * 8;          // u16 per B array per kb slice

    int t = threadIdx.x;
    int w = t >> 6, l = t & 63;
    int m0 = blockIdx.x * 128 + w * 16;
    int lm = l & 15, q = l >> 4;

    int arow = min(m0 + lm, n - 1);
    const u16* aH = Ahi + (size_t)arow * 256 + q * 8;
    const u16* aL = Alo + (size_t)arow * 256 + q * 8;

    floatx4 acc[CT] = {};

    auto stageB = [&](int buf, int kb) {
        u16* L = ldsb + (size_t)buf * (2 * BSZ);
        constexpr int BROUNDS = (BFRAG + THREADS - 1) / THREADS;
#pragma unroll
        for (int r = 0; r < BROUNDS; ++r) {
            int u = r * THREADS + t;
            if ((BFRAG % THREADS == 0) || u < BFRAG) {
                size_t off = ((size_t)kb * BFRAG + (size_t)u) * 8;
                u16* Lb = L + (size_t)(r * THREADS + w * 64) * 8;
                load16(Bhi + off, Lb);
                load16(Blo + off, Lb + BSZ);
            }
        }
    };

    stageB(0, 0);
    bf16x8 ahi = *(const bf16x8*)aH;
    bf16x8 alo = *(const bf16x8*)aL;
    __syncthreads();

    for (int kb = 0; kb < 8; ++kb) {
        int cur = kb & 1;
        bf16x8 nhi = ahi, nlo = alo;
        if (kb < 7) {
            stageB(cur ^ 1, kb + 1);
            nhi = *(const bf16x8*)(aH + (kb + 1) * 32);
            nlo = *(const bf16x8*)(aL + (kb + 1) * 32);
        }
        const u16* L = ldsb + (size_t)cur * (2 * BSZ);
#pragma unroll
        for (int ct = 0; ct < CT; ++ct) {
            bf16x8 bhi = *(const bf16x8*)&L[(ct * 64 + l) * 8];
            bf16x8 blo = *(const bf16x8*)&L[BSZ + (ct * 64 + l) * 8];
            acc[ct] = __builtin_amdgcn_mfma_f32_16x16x32_bf16(ahi, bhi, acc[ct], 0, 0, 0);
            acc[ct] = __builtin_amdgcn_mfma_f32_16x16x32_bf16(alo, bhi, acc[ct], 0, 0, 0);
            acc[ct] = __builtin_amdgcn_mfma_f32_16x16x32_bf16(ahi, blo, acc[ct], 0, 0, 0);
        }
        __syncthreads();
        ahi = nhi; alo = nlo;
    }

#pragma unroll
    for (int ct = 0; ct < CT; ++ct) {
#pragma unroll
        for (int r = 0; r < 4; ++r) {
            int row = m0 + q * 4 + r;
            if (row < n)
                Hb[(size_t)row * (CT * 16) + ct * 16 + lm] = f2b(acc[ct][r]);
        }
    }
    constexpr int CPH = CT / HEADS;
    float ps[4][HEADS] = {}, pd[4][HEADS] = {};
#pragma unroll
    for (int h = 0; h < HEADS; ++h) {
#pragma unroll
        for (int j = 0; j < CPH; ++j) {
            int ct = h * CPH + j;
            float a_s = asrc[ct * 16 + lm];
            float a_d = adst[ct * 16 + lm];
#pragma unroll
            for (int r = 0; r < 4; ++r) {
                ps[r][h] = fmaf(acc[ct][r], a_s, ps[r][h]);
                pd[r][h] = fmaf(acc[ct][r], a_d, pd[r][h]);
            }
        }
    }
#pragma unroll
    for (int r = 0; r < 4; ++r)
#pragma unroll
        for (int h = 0; h < HEADS; ++h)
#pragma unroll
            for (int o = 1; o < 16; o <<= 1) {
                ps[r][h] += __shfl_xor(ps[r][h], o);
                pd[r][h] += __shfl_xor(pd[r][h], o);
            }
#pragma unroll
    for (int h = 0; h < HEADS; ++h) {
        if (lm == h) {
#pragma unroll
            for (int r = 0; r < 4; ++r) {
                int row = m0 + q * 4 + r;
                if (row < n) {
                    ssrc[row * HEADS + h] = ps[r][h];
                    sdst[row * HEADS + h] = pd[r][h];
                }
            }
        }
    }
}

// ---------------- K2: layer-2 GEMM (unchanged R13 structure) --------------

template <int CT, int HEADS>
__global__ __launch_bounds__(512, 4) void gemm_async(const u16* __restrict__ Ahi,
                                                     const u16* __restrict__ Alo,
                                                     const u16* __restrict__ Bhi,
                                                     const u16* __restrict__ Blo,
                                                     const float* __restrict__ asrc,
                                                     const float* __restrict__ adst,
                                                     u16* __restrict__ Hb,
                                                     float* __restrict__ ssrc,
                                                     float* __restrict__ sdst, int n) {
    __shared__ __align__(16) u16 lds[2][2 * CT * 64 * 8];
    gemm_phase<CT, HEADS>(&lds[0][0], Ahi, Alo, Bhi, Blo, asrc, adst, Hb, ssrc, sdst, n);
}

// ---------------- K1: CSR build + prep + layer-1 aggregation --------------

__global__ __launch_bounds__(NT, 8) void fused_front(
    const float* __restrict__ x, const int* __restrict__ ei,
    const float* __restrict__ W1, const float* __restrict__ as1,
    const float* __restrict__ ad1, const float* __restrict__ b1,
    const float* __restrict__ W2, const float* __restrict__ W3,
    u16* __restrict__ B2h, u16* __restrict__ B2l,
    u16* __restrict__ B3h, u16* __restrict__ B3l,
    float* __restrict__ vsd,
    int* __restrict__ deg, int* __restrict__ offs, int* __restrict__ cursor,
    int* __restrict__ csr, int* __restrict__ bar,
    u16* __restrict__ Fhi, u16* __restrict__ Flo, int n, int E) {
    const int tid = threadIdx.x;
    const int b = blockIdx.x;
    const int tg = b * NT + tid;
    const int NTH = NB1 * NT;
    const int Etot = E + n;
    const int lane = tid & 63;

    // ---- P0: zero deg + pack W2/W3 + l1_prep ----
    for (int i = tg; i < n; i += NTH) deg[i] = 0;
    if (tg < 8192) {
        pack_dev(W2, B2h, B2l, 256, tg);
    } else if (tg < 9216) {
        pack_dev(W3, B3h, B3l, 32, tg - 8192);
    } else if (tg < 9472) {
        int j = tg - 9216;                 // 0..255, wave-aligned (9216%64==0)
        float a_s = as1[j], a_d = ad1[j];
#pragma unroll
        for (int k = 0; k < 3; ++k) {
            float w = W1[k * 256 + j];
            float ps = w * a_s, pd = w * a_d;
#pragma unroll
            for (int o = 32; o > 0; o >>= 1) {
                ps += __shfl_xor(ps, o);
                pd += __shfl_xor(pd, o);
            }
            if (lane == 0) {
                vsd[(j >> 6) * 3 + k] = ps;
                vsd[12 + (j >> 6) * 3 + k] = pd;
            }
        }
    }
    gridbar(bar, NB1);

    // ---- P1: edge count ----
    for (int e = tg; e < Etot; e += NTH) {
        int dst = (e < E) ? ei[E + e] : (e - E);
        atomicAdd(&deg[dst], 1);
    }
    gridbar(bar, NB1);

    // ---- P2: wave-atomic segment allocation (replaces 3-phase scan) ----
    // Each wave: shfl_up prefix over 64 degrees, 1 atomicAdd for its base.
    {
        int wid = tg >> 6;
        int i = wid * 64 + lane;
        int v = (i < n) ? deg[i] : 0;
        int incl = v;
#pragma unroll
        for (int o = 1; o < 64; o <<= 1) {
            int t2 = __shfl_up(incl, o);
            if (lane >= o) incl += t2;
        }
        int base = 0;
        if (lane == 63 && incl > 0) base = atomicAdd(&bar[64], incl);
        base = __shfl(base, 63);
        if (i < n) { int beg = base + incl - v; offs[i] = beg; cursor[i] = beg; }
    }
    gridbar(bar, NB1);

    // ---- P3: edge fill ----
    for (int e = tg; e < Etot; e += NTH) {
        int src, dst;
        if (e < E) { src = ei[e]; dst = ei[E + e]; }
        else       { src = e - E; dst = e - E; }
        int pos = atomicAdd(&cursor[dst], 1);
        csr[pos] = src;
    }
    gridbar(bar, NB1);

    // ---- P4: layer-1 x-space aggregation ----
    {
        int wid = b * 8 + (tid >> 6);
        for (int node = wid; node < n; node += NB1 * 8)
            agg_l1_node(node, lane, x, vsd, offs, deg, csr, W1, b1, Fhi, Flo);
    }
}

// ---------------- K3: agg_m4(L2) -> gemm3 -> agg_h1 -----------------------

__global__ __launch_bounds__(NT, 8) void fused_back(
    const u16* __restrict__ B3h, const u16* __restrict__ B3l,
    const float* __restrict__ as3, const float* __restrict__ ad3,
    const float* __restrict__ b2, const float* __restrict__ b3,
    u16* __restrict__ Fhi, u16* __restrict__ Flo,
    const u16* __restrict__ Hb, u16* __restrict__ Hb3,
    float* __restrict__ ssrc, float* __restrict__ sdst,
    const int* __restrict__ offs, const int* __restrict__ deg,
    const int* __restrict__ csr,
    int* __restrict__ bar, float* __restrict__ out, int n) {
    __shared__ __align__(16) u16 lds3[4096];   // 8 KB: CT=2 double-buffer
    const int tid = threadIdx.x;
    const int b = blockIdx.x;
    const int wid = b * 8 + (tid >> 6);
    const int lane = tid & 63;

    // ---- P5: layer-2 aggregation (reads Hb/ssrc/sdst; writes Fhi/Flo) ----
    for (int node = wid; node < n; node += NB3 * 8)
        agg_m4_node(node, lane, Hb, ssrc, sdst, offs, deg, csr, b2, Fhi, Flo);
    gridbar(bar, NB3);

    // ---- P6: layer-3 GEMM (reads Fhi/Flo; writes Hb3, ssrc/sdst str.1) ---
    if (b < NTILES)
        gemm_phase<2, 1>(&lds3[0], Fhi, Flo, B3h, B3l, as3, ad3, Hb3, ssrc, sdst, n);
    gridbar(bar, NB3);

    // ---- P7: layer-3 aggregation -> out ----
    for (int node = wid; node < n; node += NB3 * 8)
        agg_h1_node(node, lane, Hb3, ssrc, sdst, offs, deg, csr, b3, out);
}

// ---------------- Launch ----------------

extern "C" void kernel_launch(void* const* d_in, const int* in_sizes, int n_in,
                              void* d_out, int out_size, void* d_ws, size_t ws_size,
                              hipStream_t stream) {
    const float* x   = (const float*)d_in[0];
    const int*   ei  = (const int*)d_in[1];
    const float* W1  = (const float*)d_in[2];
    const float* as1 = (const float*)d_in[3];
    const float* ad1 = (const float*)d_in[4];
    const float* b1  = (const float*)d_in[5];
    const float* W2  = (const float*)d_in[6];
    const float* as2 = (const float*)d_in[7];
    const float* ad2 = (const float*)d_in[8];
    const float* b2  = (const float*)d_in[9];
    const float* W3  = (const float*)d_in[10];
    const float* as3 = (const float*)d_in[11];
    const float* ad3 = (const float*)d_in[12];
    const float* b3  = (const float*)d_in[13];
    float* out = (float*)d_out;

    const int n = in_sizes[0] / 3;     // 50000
    const int E = in_sizes[1] / 2;     // 400000
    const int Etot = E + n;            // with self-loops

    // workspace layout (~84 MB)
    char* ws = (char*)d_ws;
    u16* Fhi  = (u16*)ws;    ws += (size_t)n * 256 * sizeof(u16);     // 25.6 MB
    u16* Flo  = (u16*)ws;    ws += (size_t)n * 256 * sizeof(u16);     // 25.6 MB
    u16* Hb   = (u16*)ws;    ws += (size_t)n * 256 * sizeof(u16);     // 25.6 MB
    u16* Hb3  = (u16*)ws;    ws += (size_t)n * 32 * sizeof(u16);      // 3.2 MB
    u16* B2h  = (u16*)ws;    ws += (size_t)8 * 16 * 64 * 8 * sizeof(u16);
    u16* B2l  = (u16*)ws;    ws += (size_t)8 * 16 * 64 * 8 * sizeof(u16);
    u16* B3h  = (u16*)ws;    ws += (size_t)8 * 2 * 64 * 8 * sizeof(u16);
    u16* B3l  = (u16*)ws;    ws += (size_t)8 * 2 * 64 * 8 * sizeof(u16);
    float* ssrc = (float*)ws;  ws += (size_t)n * 4 * sizeof(float);
    float* sdst = (float*)ws;  ws += (size_t)n * 4 * sizeof(float);
    float* vsd  = (float*)ws;  ws += 32 * sizeof(float);
    int* deg    = (int*)ws;    ws += (size_t)n * sizeof(int);
    int* offs   = (int*)ws;    ws += (size_t)(n + 1) * sizeof(int) + 12;
    int* cursor = (int*)ws;    ws += (size_t)n * sizeof(int);
    int* bar    = (int*)ws;    ws += 128 * sizeof(int);   // cnt/gen/alloc lines
    int* csr    = (int*)ws;    ws += (size_t)Etot * sizeof(int);   // keep csr LAST

    // ---- reset barrier state (cnt, gen, alloc counter) ----
    hipMemsetAsync(bar, 0, 128 * sizeof(int), stream);

    // ---- K1: CSR + prep + layer 1 ----
    fused_front<<<NB1, NT, 0, stream>>>(x, ei, W1, as1, ad1, b1, W2, W3,
                                        B2h, B2l, B3h, B3l, vsd,
                                        deg, offs, cursor, csr, bar,
                                        Fhi, Flo, n, E);

    // ---- K2: layer-2 GEMM ----
    gemm_async<16, 4><<<NTILES, NT, 0, stream>>>(Fhi, Flo, B2h, B2l, as2, ad2,
                                                 Hb, ssrc, sdst, n);

    // ---- K3: layer-2 agg + layer-3 GEMM + layer-3 agg ----
    fused_back<<<NB3, NT, 0, stream>>>(B3h, B3l, as3, ad3, b2, b3,
                                       Fhi, Flo, Hb, Hb3, ssrc, sdst,
                                       offs, deg, csr, bar, out, n);
}

// Round 9
// 294.383 us; speedup vs baseline: 6.3724x; 4.8629x over previous
//
#include <hip/hip_runtime.h>
#include <math.h>

// =====================================================================
// 3-layer GAT (PyG GATConv) on MI355X.
// R17: R14 structure, dispatches 14 -> 9, NO device barriers (R15/R16
// showed grid-barrier arrival costs ~0.3us/block serialized = 150-320us
// per crossing -- kernel boundaries are 10-30x cheaper).
//  - prep_count: edge_count || pack(W2) || pack(W3) || l1_prep (4->1).
//  - alloc_offs: wave-atomic segment allocation (shfl prefix + 1 atomic
//    per wave) replaces the 3-kernel scan (3->1); segment order is
//    arbitrary, consumers use end = offs[node] + deg[node] (R16-proven).
//  - agg_l1 (x-space layer 1), gemm_async BM=128 (R13), agg_m4, agg_h1
//    bodies unchanged from their proven forms.
// =====================================================================

#define NEG_SLOPE 0.2f

typedef unsigned short u16;
typedef short bf16x8 __attribute__((ext_vector_type(8)));
typedef float floatx4 __attribute__((ext_vector_type(4)));

__device__ __forceinline__ float b2f(u16 u) {
    return __uint_as_float(((unsigned int)u) << 16);
}
__device__ __forceinline__ u16 f2b(float f) {
    unsigned int u = __float_as_uint(f);
    unsigned int r = (u + 0x7fffu + ((u >> 16) & 1u)) >> 16;   // RNE
    return (u16)r;
}
__device__ __forceinline__ void load16(const u16* g, u16* l) {
    __builtin_amdgcn_global_load_lds(
        (const __attribute__((address_space(1))) void*)g,
        (__attribute__((address_space(3))) void*)l, 16, 0, 0);
}

// -------- Pack W into MFMA-fragment-major hi/lo bf16 (device) -------------

__device__ __forceinline__ void pack_dev(const float* __restrict__ W,
                                         u16* __restrict__ Bhi,
                                         u16* __restrict__ Blo, int N, int idx) {
    int CT = N / 16;
    int lane = idx & 63;
    int ctkb = idx >> 6;
    int ct = ctkb % CT;
    int kb = ctkb / CT;
    int col = ct * 16 + (lane & 15);
    int k0 = kb * 32 + (lane >> 4) * 8;
#pragma unroll
    for (int j = 0; j < 8; ++j) {
        float w = W[(size_t)(k0 + j) * N + col];
        u16 hi = f2b(w);
        Bhi[(size_t)idx * 8 + j] = hi;
        Blo[(size_t)idx * 8 + j] = f2b(w - b2f(hi));
    }
}

// ---- K1: edge_count || pack W2 || pack W3 || l1_prep (all independent) ---

__global__ __launch_bounds__(256) void prep_count(
    const int* __restrict__ ei,
    const float* __restrict__ W1, const float* __restrict__ as1,
    const float* __restrict__ ad1,
    const float* __restrict__ W2, const float* __restrict__ W3,
    u16* __restrict__ B2h, u16* __restrict__ B2l,
    u16* __restrict__ B3h, u16* __restrict__ B3l,
    float* __restrict__ vsd, int* __restrict__ deg, int n, int E) {
    const int tid = threadIdx.x;
    const int tg = blockIdx.x * 256 + tid;
    const int NTH = gridDim.x * 256;
    const int Etot = E + n;
    const int lane = tid & 63;

    if (tg < 8192) {
        pack_dev(W2, B2h, B2l, 256, tg);
    } else if (tg < 9216) {
        pack_dev(W3, B3h, B3l, 32, tg - 8192);
    } else if (tg < 9472) {
        int j = tg - 9216;                 // 0..255, wave-aligned
        float a_s = as1[j], a_d = ad1[j];
#pragma unroll
        for (int k = 0; k < 3; ++k) {
            float w = W1[k * 256 + j];
            float ps = w * a_s, pd = w * a_d;
#pragma unroll
            for (int o = 32; o > 0; o >>= 1) {
                ps += __shfl_xor(ps, o);
                pd += __shfl_xor(pd, o);
            }
            if (lane == 0) {
                vsd[(j >> 6) * 3 + k] = ps;
                vsd[12 + (j >> 6) * 3 + k] = pd;
            }
        }
    }
    for (int e = tg; e < Etot; e += NTH) {
        int dst = (e < E) ? ei[E + e] : (e - E);
        atomicAdd(&deg[dst], 1);
    }
}

// ---- K2: wave-atomic segment allocation (replaces 3-phase scan) ----------
// Each wave: shfl_up prefix over 64 degrees + 1 atomicAdd for its base.
// Segment order arbitrary; consumers use end = offs[i] + deg[i].

__global__ __launch_bounds__(256) void alloc_offs(int* __restrict__ deg,
                                                  int* __restrict__ offs,
                                                  int* __restrict__ cursor,
                                                  int* __restrict__ alloc, int n) {
    int lane = threadIdx.x & 63;
    int wid = (blockIdx.x * 256 + threadIdx.x) >> 6;
    int i = wid * 64 + lane;
    int v = (i < n) ? deg[i] : 0;
    int incl = v;
#pragma unroll
    for (int o = 1; o < 64; o <<= 1) {
        int t2 = __shfl_up(incl, o);
        if (lane >= o) incl += t2;
    }
    int base = 0;
    if (lane == 63 && incl > 0) base = atomicAdd(alloc, incl);
    base = __shfl(base, 63);
    if (i < n) { int beg = base + incl - v; offs[i] = beg; cursor[i] = beg; }
}

// ---- K3: edge fill -------------------------------------------------------

__global__ __launch_bounds__(256) void edge_fill(const int* __restrict__ ei, int E, int n,
                                                 int* __restrict__ cursor,
                                                 int* __restrict__ csr) {
    int e = blockIdx.x * blockDim.x + threadIdx.x;
    int Etot = E + n;
    if (e >= Etot) return;
    int src, dst;
    if (e < E) { src = ei[e]; dst = ei[E + e]; }
    else       { src = e - E; dst = e - E; }
    int pos = atomicAdd(&cursor[dst], 1);
    csr[pos] = src;
}

// ---------------- K4: layer-1 x-space aggregation -------------------------
// One wave per dst node. Softmax lanes: head hB=lane&3, edge slot eL=lane>>2
// (s_src = 3-dot of gathered x row with v_s[hB]); aggregate sum_e alpha*x
// in registers (shuffle-only consume); epilogue applies W1, hi/lo bf16 out.

__global__ __launch_bounds__(256) void gat_aggregate_l1(const float* __restrict__ x,
                                                        const float* __restrict__ vsd,
                                                        const int* __restrict__ offs,
                                                        const int* __restrict__ deg,
                                                        const int* __restrict__ csr,
                                                        const float* __restrict__ W1,
                                                        const float* __restrict__ bias,
                                                        u16* __restrict__ outHi,
                                                        u16* __restrict__ outLo, int n) {
    int node = blockIdx.x * 4 + (threadIdx.x >> 6);
    int lane = threadIdx.x & 63;
    if (node >= n) return;
    const int hB = lane & 3;
    const int eL = lane >> 2;
    const int hA = lane >> 4;
    int beg = offs[node], end = beg + deg[node];

    float vs0 = vsd[hB * 3 + 0], vs1 = vsd[hB * 3 + 1], vs2 = vsd[hB * 3 + 2];
    float vd0 = vsd[12 + hB * 3 + 0], vd1 = vsd[12 + hB * 3 + 1], vd2 = vsd[12 + hB * 3 + 2];
    float xd0 = x[node * 3 + 0], xd1 = x[node * 3 + 1], xd2 = x[node * 3 + 2];
    float sd = fmaf(xd0, vd0, fmaf(xd1, vd1, xd2 * vd2));

    float m = -INFINITY, l = 0.f;
    float ax = 0.f, ay = 0.f, az = 0.f;

    for (int base = beg; base < end; base += 16) {
        int j = base + eL;
        bool valid = (j < end);
        int sj = valid ? csr[j] : 0;
        float x0 = x[sj * 3 + 0];
        float x1 = x[sj * 3 + 1];
        float x2 = x[sj * 3 + 2];
        float logit = -INFINITY;
        if (valid) {
            float xv = fmaf(x0, vs0, fmaf(x1, vs1, x2 * vs2)) + sd;
            logit = (xv > 0.f) ? xv : NEG_SLOPE * xv;
        }
        float cm = logit;
        cm = fmaxf(cm, __shfl_xor(cm, 4));
        cm = fmaxf(cm, __shfl_xor(cm, 8));
        cm = fmaxf(cm, __shfl_xor(cm, 16));
        cm = fmaxf(cm, __shfl_xor(cm, 32));
        float nm = fmaxf(m, cm);
        float scale = __expf(m - nm);
        float ex = valid ? __expf(logit - nm) : 0.f;
        float es = ex;
        es += __shfl_xor(es, 4);
        es += __shfl_xor(es, 8);
        es += __shfl_xor(es, 16);
        es += __shfl_xor(es, 32);
        l = l * scale + es;
        m = nm;
        float sA = __shfl(scale, hA);
        ax *= sA; ay *= sA; az *= sA;

        int cnt = min(16, end - base);
        for (int t = 0; t < cnt; ++t) {
            float a  = __shfl(ex, t * 4 + hA);
            float bx = __shfl(x0, t * 4);
            float by = __shfl(x1, t * 4);
            float bz = __shfl(x2, t * 4);
            ax = fmaf(a, bx, ax);
            ay = fmaf(a, by, ay);
            az = fmaf(a, bz, az);
        }
    }

    float lf = __shfl(l, hA);
    float inv = 1.f / lf;
    ax *= inv; ay *= inv; az *= inv;

    int c = lane * 4;
    const float4 w0 = *(const float4*)&W1[0 * 256 + c];
    const float4 w1 = *(const float4*)&W1[1 * 256 + c];
    const float4 w2 = *(const float4*)&W1[2 * 256 + c];
    const float4 bv = *(const float4*)&bias[c];
    float4 o;
    o.x = fmaxf(fmaf(ax, w0.x, fmaf(ay, w1.x, fmaf(az, w2.x, bv.x))), 0.f);
    o.y = fmaxf(fmaf(ax, w0.y, fmaf(ay, w1.y, fmaf(az, w2.y, bv.y))), 0.f);
    o.z = fmaxf(fmaf(ax, w0.z, fmaf(ay, w1.z, fmaf(az, w2.z, bv.z))), 0.f);
    o.w = fmaxf(fmaf(ax, w0.w, fmaf(ay, w1.w, fmaf(az, w2.w, bv.w))), 0.f);
    ushort4 h4, l4;
    h4.x = f2b(o.x); l4.x = f2b(o.x - b2f(h4.x));
    h4.y = f2b(o.y); l4.y = f2b(o.y - b2f(h4.y));
    h4.z = f2b(o.z); l4.z = f2b(o.z - b2f(h4.z));
    h4.w = f2b(o.w); l4.w = f2b(o.w - b2f(h4.w));
    *(ushort4*)&outHi[(size_t)node * 256 + c] = h4;
    *(ushort4*)&outLo[(size_t)node * 256 + c] = l4;
}

// ------- K5/K7: async 2-phase split-precision MFMA GEMM, BM=128 -----------

template <int CT, int HEADS>
__global__ __launch_bounds__(512, 4) void gemm_async(const u16* __restrict__ Ahi,
                                                     const u16* __restrict__ Alo,
                                                     const u16* __restrict__ Bhi,
                                                     const u16* __restrict__ Blo,
                                                     const float* __restrict__ asrc,
                                                     const float* __restrict__ adst,
                                                     u16* __restrict__ Hb,
                                                     float* __restrict__ ssrc,
                                                     float* __restrict__ sdst, int n) {
    constexpr int THREADS = 512;
    constexpr int BFRAG = CT * 64;          // B 16B-chunks per kb per array
    constexpr int BSZ = BFRAG * 8;          // u16 per B array per kb slice
    __shared__ __align__(16) u16 lds[2][2 * BSZ];

    int t = threadIdx.x;
    int w = t >> 6, l = t & 63;
    int m0 = blockIdx.x * 128 + w * 16;     // 8 waves x 16 rows
    int lm = l & 15, q = l >> 4;

    int arow = min(m0 + lm, n - 1);
    const u16* aH = Ahi + (size_t)arow * 256 + q * 8;
    const u16* aL = Alo + (size_t)arow * 256 + q * 8;

    floatx4 acc[CT] = {};

    auto stageB = [&](int buf, int kb) {
        u16* L = &lds[buf][0];
        constexpr int BROUNDS = (BFRAG + THREADS - 1) / THREADS;
#pragma unroll
        for (int r = 0; r < BROUNDS; ++r) {
            int u = r * THREADS + t;
            if ((BFRAG % THREADS == 0) || u < BFRAG) {
                size_t off = ((size_t)kb * BFRAG + (size_t)u) * 8;
                u16* Lb = L + (size_t)(r * THREADS + w * 64) * 8;   // wave-uniform
                load16(Bhi + off, Lb);
                load16(Blo + off, Lb + BSZ);
            }
        }
    };

    stageB(0, 0);
    bf16x8 ahi = *(const bf16x8*)aH;
    bf16x8 alo = *(const bf16x8*)aL;
    __syncthreads();

    for (int kb = 0; kb < 8; ++kb) {
        int cur = kb & 1;
        bf16x8 nhi = ahi, nlo = alo;
        if (kb < 7) {
            stageB(cur ^ 1, kb + 1);
            nhi = *(const bf16x8*)(aH + (kb + 1) * 32);
            nlo = *(const bf16x8*)(aL + (kb + 1) * 32);
        }
        const u16* L = &lds[cur][0];
#pragma unroll
        for (int ct = 0; ct < CT; ++ct) {
            bf16x8 bhi = *(const bf16x8*)&L[(ct * 64 + l) * 8];
            bf16x8 blo = *(const bf16x8*)&L[BSZ + (ct * 64 + l) * 8];
            acc[ct] = __builtin_amdgcn_mfma_f32_16x16x32_bf16(ahi, bhi, acc[ct], 0, 0, 0);
            acc[ct] = __builtin_amdgcn_mfma_f32_16x16x32_bf16(alo, bhi, acc[ct], 0, 0, 0);
            acc[ct] = __builtin_amdgcn_mfma_f32_16x16x32_bf16(ahi, blo, acc[ct], 0, 0, 0);
        }
        __syncthreads();
        ahi = nhi; alo = nlo;
    }

#pragma unroll
    for (int ct = 0; ct < CT; ++ct) {
#pragma unroll
        for (int r = 0; r < 4; ++r) {
            int row = m0 + q * 4 + r;
            if (row < n)
                Hb[(size_t)row * (CT * 16) + ct * 16 + lm] = f2b(acc[ct][r]);
        }
    }
    constexpr int CPH = CT / HEADS;
    float ps[4][HEADS] = {}, pd[4][HEADS] = {};
#pragma unroll
    for (int h = 0; h < HEADS; ++h) {
#pragma unroll
        for (int j = 0; j < CPH; ++j) {
            int ct = h * CPH + j;
            float a_s = asrc[ct * 16 + lm];
            float a_d = adst[ct * 16 + lm];
#pragma unroll
            for (int r = 0; r < 4; ++r) {
                ps[r][h] = fmaf(acc[ct][r], a_s, ps[r][h]);
                pd[r][h] = fmaf(acc[ct][r], a_d, pd[r][h]);
            }
        }
    }
#pragma unroll
    for (int r = 0; r < 4; ++r)
#pragma unroll
        for (int h = 0; h < HEADS; ++h)
#pragma unroll
            for (int o = 1; o < 16; o <<= 1) {
                ps[r][h] += __shfl_xor(ps[r][h], o);
                pd[r][h] += __shfl_xor(pd[r][h], o);
            }
#pragma unroll
    for (int h = 0; h < HEADS; ++h) {
        if (lm == h) {
#pragma unroll
            for (int r = 0; r < 4; ++r) {
                int row = m0 + q * 4 + r;
                if (row < n) {
                    ssrc[row * HEADS + h] = ps[r][h];
                    sdst[row * HEADS + h] = pd[r][h];
                }
            }
        }
    }
}

// ---------------- K6: merged 4-head aggregation (layer 2) -----------------

__global__ __launch_bounds__(256) void gat_aggregate_m4(const u16* __restrict__ Hb,
                                                        const float* __restrict__ ssrc,
                                                        const float* __restrict__ sdst,
                                                        const int* __restrict__ offs,
                                                        const int* __restrict__ deg,
                                                        const int* __restrict__ csr,
                                                        const float* __restrict__ bias,
                                                        u16* __restrict__ outHi,
                                                        u16* __restrict__ outLo, int n) {
    int node = blockIdx.x * 4 + (threadIdx.x >> 6);
    int lane = threadIdx.x & 63;
    if (node >= n) return;
    const int hB = lane & 3;
    const int eL = lane >> 2;
    const int hA = lane >> 4;
    int beg = offs[node], end = beg + deg[node];
    float sd = sdst[node * 4 + hB];
    float m = -INFINITY, l = 0.f;
    float4 acc = make_float4(0.f, 0.f, 0.f, 0.f);

    for (int base = beg; base < end; base += 16) {
        int j = base + eL;
        bool valid = (j < end);
        int sj = valid ? csr[j] : 0;
        float logit = -INFINITY;
        if (valid) {
            float xv = ssrc[sj * 4 + hB] + sd;
            logit = (xv > 0.f) ? xv : NEG_SLOPE * xv;
        }
        float cm = logit;
        cm = fmaxf(cm, __shfl_xor(cm, 4));
        cm = fmaxf(cm, __shfl_xor(cm, 8));
        cm = fmaxf(cm, __shfl_xor(cm, 16));
        cm = fmaxf(cm, __shfl_xor(cm, 32));
        float nm = fmaxf(m, cm);
        float scale = __expf(m - nm);
        float ex = valid ? __expf(logit - nm) : 0.f;
        float es = ex;
        es += __shfl_xor(es, 4);
        es += __shfl_xor(es, 8);
        es += __shfl_xor(es, 16);
        es += __shfl_xor(es, 32);
        l = l * scale + es;
        m = nm;
        float sA = __shfl(scale, hA);
        acc.x *= sA; acc.y *= sA; acc.z *= sA; acc.w *= sA;

        int cnt = min(16, end - base);
        for (int t = 0; t < cnt; t += 4) {
#pragma unroll
            for (int u = 0; u < 4; ++u) {
                int tt = t + u;
                float a = __shfl(ex, tt * 4 + hA);
                int s = __shfl(sj, tt * 4);
                ushort4 hv = *(const ushort4*)&Hb[(size_t)s * 256 + lane * 4];
                acc.x = fmaf(a, b2f(hv.x), acc.x);
                acc.y = fmaf(a, b2f(hv.y), acc.y);
                acc.z = fmaf(a, b2f(hv.z), acc.z);
                acc.w = fmaf(a, b2f(hv.w), acc.w);
            }
        }
    }
    float lf = __shfl(l, hA);
    float inv = 1.f / lf;
    const float4 bv = *(const float4*)&bias[lane * 4];
    float4 o;
    o.x = fmaxf(fmaf(acc.x, inv, bv.x), 0.f);
    o.y = fmaxf(fmaf(acc.y, inv, bv.y), 0.f);
    o.z = fmaxf(fmaf(acc.z, inv, bv.z), 0.f);
    o.w = fmaxf(fmaf(acc.w, inv, bv.w), 0.f);
    ushort4 h4, l4;
    h4.x = f2b(o.x); l4.x = f2b(o.x - b2f(h4.x));
    h4.y = f2b(o.y); l4.y = f2b(o.y - b2f(h4.y));
    h4.z = f2b(o.z); l4.z = f2b(o.z - b2f(h4.z));
    h4.w = f2b(o.w); l4.w = f2b(o.w - b2f(h4.w));
    *(ushort4*)&outHi[(size_t)node * 256 + lane * 4] = h4;
    *(ushort4*)&outLo[(size_t)node * 256 + lane * 4] = l4;
}

// ---------------- K8: single-head aggregation (layer 3) -------------------

__global__ __launch_bounds__(256) void gat_aggregate_h1(const u16* __restrict__ Hb,
                                                        const float* __restrict__ ssrc,
                                                        const float* __restrict__ sdst,
                                                        const int* __restrict__ offs,
                                                        const int* __restrict__ deg,
                                                        const int* __restrict__ csr,
                                                        const float* __restrict__ bias,
                                                        float* __restrict__ out, int n) {
    int node = blockIdx.x * 4 + (threadIdx.x >> 6);
    int lane = threadIdx.x & 63;
    if (node >= n) return;
    int beg = offs[node], end = beg + deg[node];
    float sd = sdst[node];
    float m = -INFINITY, l = 0.f, acc = 0.f;

    for (int base = beg; base < end; base += 64) {
        int j = base + lane;
        bool valid = (j < end);
        int sj = valid ? csr[j] : 0;
        float logit = -INFINITY;
        if (valid) {
            float xv = ssrc[sj] + sd;
            logit = (xv > 0.f) ? xv : NEG_SLOPE * xv;
        }
        float cm = logit;
#pragma unroll
        for (int o = 32; o > 0; o >>= 1) cm = fmaxf(cm, __shfl_xor(cm, o));
        float nm = fmaxf(m, cm);
        float scale = __expf(m - nm);
        float ex = valid ? __expf(logit - nm) : 0.f;
        float es = ex;
#pragma unroll
        for (int o = 32; o > 0; o >>= 1) es += __shfl_xor(es, o);
        l = l * scale + es;
        m = nm;
        acc *= scale;
        int cnt = min(64, end - base);
        for (int t = 0; t < cnt; t += 4) {
#pragma unroll
            for (int u = 0; u < 4; ++u) {
                float a = __shfl(ex, t + u);
                int s = __shfl(sj, t + u);
                if (lane < 32) acc = fmaf(a, b2f(Hb[(size_t)s * 32 + lane]), acc);
            }
        }
    }
    if (lane < 32) out[(size_t)node * 32 + lane] = acc / l + bias[lane];
}

// ---------------- Launch ----------------

extern "C" void kernel_launch(void* const* d_in, const int* in_sizes, int n_in,
                              void* d_out, int out_size, void* d_ws, size_t ws_size,
                              hipStream_t stream) {
    const float* x   = (const float*)d_in[0];
    const int*   ei  = (const int*)d_in[1];
    const float* W1  = (const float*)d_in[2];
    const float* as1 = (const float*)d_in[3];
    const float* ad1 = (const float*)d_in[4];
    const float* b1  = (const float*)d_in[5];
    const float* W2  = (const float*)d_in[6];
    const float* as2 = (const float*)d_in[7];
    const float* ad2 = (const float*)d_in[8];
    const float* b2  = (const float*)d_in[9];
    const float* W3  = (const float*)d_in[10];
    const float* as3 = (const float*)d_in[11];
    const float* ad3 = (const float*)d_in[12];
    const float* b3  = (const float*)d_in[13];
    float* out = (float*)d_out;

    const int n = in_sizes[0] / 3;     // 50000
    const int E = in_sizes[1] / 2;     // 400000
    const int Etot = E + n;            // with self-loops

    // workspace layout (~84 MB)
    char* ws = (char*)d_ws;
    u16* Fhi  = (u16*)ws;    ws += (size_t)n * 256 * sizeof(u16);     // 25.6 MB
    u16* Flo  = (u16*)ws;    ws += (size_t)n * 256 * sizeof(u16);     // 25.6 MB
    u16* Hb   = (u16*)ws;    ws += (size_t)n * 256 * sizeof(u16);     // 25.6 MB
    u16* Hb3  = (u16*)ws;    ws += (size_t)n * 32 * sizeof(u16);      // 3.2 MB
    u16* B2h  = (u16*)ws;    ws += (size_t)8 * 16 * 64 * 8 * sizeof(u16);
    u16* B2l  = (u16*)ws;    ws += (size_t)8 * 16 * 64 * 8 * sizeof(u16);
    u16* B3h  = (u16*)ws;    ws += (size_t)8 * 2 * 64 * 8 * sizeof(u16);
    u16* B3l  = (u16*)ws;    ws += (size_t)8 * 2 * 64 * 8 * sizeof(u16);
    float* ssrc = (float*)ws;  ws += (size_t)n * 4 * sizeof(float);
    float* sdst = (float*)ws;  ws += (size_t)n * 4 * sizeof(float);
    float* vsd  = (float*)ws;  ws += 32 * sizeof(float);
    int* deg    = (int*)ws;    ws += (size_t)(n + 1) * sizeof(int);   // +1 = alloc ctr
    int* offs   = (int*)ws;    ws += (size_t)n * sizeof(int);
    int* cursor = (int*)ws;    ws += (size_t)n * sizeof(int);
    int* csr    = (int*)ws;    ws += (size_t)Etot * sizeof(int);   // keep csr LAST

    int* alloc = deg + n;              // covered by the single memset

    // ---- K0: zero deg + alloc counter (one memset) ----
    hipMemsetAsync(deg, 0, (size_t)(n + 1) * sizeof(int), stream);

    int eblocks = (Etot + 255) / 256;
    int nb4 = (n + 3) / 4;
    int nb128 = (n + 127) / 128;       // 391 gemm tiles
    int ablocks = (n + 64 * 4 - 1) / (64 * 4);   // alloc: 4 waves/block

    // ---- K1: edge_count || pack W2/W3 || l1_prep ----
    prep_count<<<eblocks, 256, 0, stream>>>(ei, W1, as1, ad1, W2, W3,
                                            B2h, B2l, B3h, B3l, vsd, deg, n, E);

    // ---- K2: segment allocation (replaces 3-kernel scan) ----
    alloc_offs<<<ablocks, 256, 0, stream>>>(deg, offs, cursor, alloc, n);

    // ---- K3: edge fill ----
    edge_fill<<<eblocks, 256, 0, stream>>>(ei, E, n, cursor, csr);

    // ---- K4: layer 1 (x-space aggregation) ----
    gat_aggregate_l1<<<nb4, 256, 0, stream>>>(x, vsd, offs, deg, csr, W1, b1,
                                              Fhi, Flo, n);

    // ---- K5: layer-2 GEMM ----
    gemm_async<16, 4><<<nb128, 512, 0, stream>>>(Fhi, Flo, B2h, B2l, as2, ad2,
                                                 Hb, ssrc, sdst, n);

    // ---- K6: layer-2 aggregation ----
    gat_aggregate_m4<<<nb4, 256, 0, stream>>>(Hb, ssrc, sdst, offs, deg, csr,
                                              b2, Fhi, Flo, n);

    // ---- K7: layer-3 GEMM ----
    gemm_async<2, 1><<<nb128, 512, 0, stream>>>(Fhi, Flo, B3h, B3l, as3, ad3,
                                                Hb3, ssrc, sdst, n);

    // ---- K8: layer-3 aggregation ----
    gat_aggregate_h1<<<nb4, 256, 0, stream>>>(Hb3, ssrc, sdst, offs, deg, csr,
                                              b3, out, n);
}